// Round 9
// baseline (89.557 us; speedup 1.0000x reference)
//
#include <hip/hip_runtime.h>
#include <hip/hip_bf16.h>

#define N_TOTAL 384
#define BS 128
#define PD 8
#define D_FEAT 131072
#define EPS 1e-6f

#define NSTRIP 256
#define COLS_PER (D_FEAT / NSTRIP)   // 512 cols per strip
#define CHUNK 32
#define NCH (COLS_PER / CHUNK)       // 16 chunks per strip
#define LROW 64                      // LDS row stride bytes, XOR-swizzled
#define NSLOT 24                     // partial subtiles per block (all 6 tiles)

typedef __attribute__((ext_vector_type(4))) float f32x4;
typedef __attribute__((ext_vector_type(8))) __bf16 bf16x8;
typedef __attribute__((ext_vector_type(4))) __bf16 bf16x4;

// Per-wave subtile assignment: 3 subtiles each, balanced.
// (A row-band, B col-band) in 64-row band units 0..5; covers the 12 diag-tile
// subtiles + 12 off-diag (upper-128-tile) subtiles exactly once.
static __device__ const int SUBA[8][3] = {
    {0,0,2},{1,1,2},{2,2,3},{3,3,3},{4,0,0},{4,1,1},{5,0,0},{5,1,1}};
static __device__ const int SUBB[8][3] = {
    {0,1,4},{0,1,5},{2,3,4},{2,3,5},{4,2,3},{5,2,3},{4,4,5},{5,4,5}};
// slot = wave*3 + s  ->  (row-band, col-band) for the reducer
static __device__ const int SRB[NSLOT] = {0,0,2, 1,1,2, 2,2,3, 3,3,3, 4,0,0, 4,1,1, 5,0,0, 5,1,1};
static __device__ const int SCB[NSLOT] = {0,1,4, 0,1,5, 2,3,4, 2,3,5, 4,2,3, 5,2,3, 4,4,5, 5,4,5};

// Symmetric accessor: only upper-triangular 128-tiles of G are populated.
__device__ __forceinline__ float gsym(const float* __restrict__ G, int i, int j) {
    return ((i >> 7) <= (j >> 7)) ? G[(size_t)i * N_TOTAL + j]
                                  : G[(size_t)j * N_TOTAL + i];
}

// ---- stage A: read X once (201 MB total), cvt in-reg, all 24 subtile partials ----
__global__ __launch_bounds__(512) void gram_fused_kernel(const float* __restrict__ X,
                                                         __bf16* __restrict__ P) {
    __shared__ char sm[2][N_TOTAL * LROW];   // 2 x 24 KB, bf16 [384][32], XOR-swizzled

    const int strip = blockIdx.x;
    const int tid  = threadIdx.x;
    const int wave = tid >> 6;
    const int lane = tid & 63;
    const int r16  = lane & 15;
    const int kg   = lane >> 4;

    const int a0 = SUBA[wave][0] * 64, b0 = SUBB[wave][0] * 64;
    const int a1 = SUBA[wave][1] * 64, b1 = SUBB[wave][1] * 64;
    const int a2 = SUBA[wave][2] * 64, b2 = SUBB[wave][2] * 64;
    const int rdoff = (kg * 16) ^ ((r16 & 7) << 4);    // read-side XOR swizzle

    const size_t cbase = (size_t)strip * COLS_PER;
    const int srow  = tid >> 3;        // 0..63, +64 per slice (6 slices = 384 rows)
    const int scolf = (tid & 7) * 4;   // float col within chunk
    const int wbase = srow * LROW + (((tid & 7) * 8) ^ ((srow & 7) << 4));

    f32x4 acc0[4][4], acc1[4][4], acc2[4][4];
#pragma unroll
    for (int m = 0; m < 4; m++)
#pragma unroll
        for (int n = 0; n < 4; n++) {
            acc0[m][n] = (f32x4)(0.0f); acc1[m][n] = (f32x4)(0.0f); acc2[m][n] = (f32x4)(0.0f);
        }

    float4 g[6];   // staged fp32 chunk: 6 float4/thread = 384x32 per block

#define LOADG(t)                                                                          \
    _Pragma("unroll") for (int s = 0; s < 6; s++)                                         \
        g[s] = *(const float4*)(X + (size_t)(srow + s * 64) * D_FEAT + cbase +            \
                                (size_t)(t) * CHUNK + scolf);

#define WRITEL(buf)                                                                       \
    _Pragma("unroll") for (int s = 0; s < 6; s++) {                                       \
        bf16x4 v;                                                                         \
        v[0] = (__bf16)g[s].x; v[1] = (__bf16)g[s].y;                                     \
        v[2] = (__bf16)g[s].z; v[3] = (__bf16)g[s].w;                                     \
        *(bf16x4*)(&sm[buf][wbase + s * 64 * LROW]) = v;                                  \
    }

#define SUBT(accX, ab, bb)                                                                \
    do {                                                                                  \
        bf16x8 af[4], bf[4];                                                              \
        _Pragma("unroll") for (int m = 0; m < 4; m++)                                     \
            af[m] = *(const bf16x8*)(bptr + (ab + m * 16 + r16) * LROW + rdoff);          \
        _Pragma("unroll") for (int n = 0; n < 4; n++)                                     \
            bf[n] = *(const bf16x8*)(bptr + (bb + n * 16 + r16) * LROW + rdoff);          \
        _Pragma("unroll") for (int m = 0; m < 4; m++)                                     \
            _Pragma("unroll") for (int n = 0; n < 4; n++)                                 \
                accX[m][n] = __builtin_amdgcn_mfma_f32_16x16x32_bf16(af[m], bf[n],        \
                                                                     accX[m][n], 0, 0, 0);\
    } while (0)

#define COMPUTE(buf)                                                                      \
    do {                                                                                  \
        const char* bptr = sm[buf];                                                       \
        SUBT(acc0, a0, b0);                                                               \
        SUBT(acc1, a1, b1);                                                               \
        SUBT(acc2, a2, b2);                                                               \
    } while (0)

    // prologue: chunk 0 staged, chunk 1 in flight
    LOADG(0);
    WRITEL(0);
    LOADG(1);
    __syncthreads();

    for (int t = 0; t < NCH; ++t) {
        const int cur = t & 1;
        COMPUTE(cur);                     // loads for t+1 stay in flight under this
        if (t + 1 < NCH) {
            WRITEL(cur ^ 1);              // waits vmcnt, cvt, stage next buffer
            if (t + 2 < NCH) LOADG(t + 2);
        }
        __syncthreads();
    }
#undef LOADG
#undef WRITEL
#undef SUBT
#undef COMPUTE

    // Epilogue: per-wave 64x64 partials as bf16, col-major (bf16x4 over rows).
    // C/D layout: ccol = lane&15, crow = (lane>>4)*4 + r.
    const int crow = (lane >> 4) * 4;
    const int ccol = lane & 15;
#define STOREP(accX, s)                                                                   \
    do {                                                                                  \
        __bf16* base = P + ((size_t)strip * NSLOT + wave * 3 + (s)) * 4096;               \
        _Pragma("unroll") for (int m = 0; m < 4; m++)                                     \
            _Pragma("unroll") for (int n = 0; n < 4; n++) {                               \
                bf16x4 v;                                                                 \
                v[0] = (__bf16)accX[m][n][0]; v[1] = (__bf16)accX[m][n][1];               \
                v[2] = (__bf16)accX[m][n][2]; v[3] = (__bf16)accX[m][n][3];               \
                *(bf16x4*)(base + (n * 16 + ccol) * 64 + m * 16 + crow) = v;              \
            }                                                                             \
    } while (0)
    STOREP(acc0, 0);
    STOREP(acc1, 1);
    STOREP(acc2, 2);
#undef STOREP
}

// ---- stage B: reduce bf16 partials over 256 strips -> G (fp32) ----
__global__ __launch_bounds__(256) void reduce_kernel(const __bf16* __restrict__ P,
                                                     float* __restrict__ G) {
    const int b     = blockIdx.x;          // 0..383
    const int chunk = b & 15;              // 16 chunks of 256 elems
    const int slot  = b >> 4;              // 0..23
    const int e     = chunk * 256 + threadIdx.x;   // 0..4095

    const __bf16* p = P + (size_t)slot * 4096 + e;
    float s = 0.0f;
#pragma unroll 16
    for (int strip = 0; strip < NSTRIP; ++strip)
        s += (float)p[(size_t)strip * NSLOT * 4096];

    const int rb  = SRB[slot] * 64;
    const int cb  = SCB[slot] * 64;
    const int col = e >> 6;
    const int row = e & 63;
    G[(size_t)(rb + row) * N_TOTAL + cb + col] = s;
}

// ---------------- denominators and loss ----------------
__global__ __launch_bounds__(128) void den_kernel(const float* __restrict__ G,
                                                  float* __restrict__ den) {
    const int i = blockIdx.x;
    __shared__ float sInv[N_TOTAL];
    for (int j = threadIdx.x; j < N_TOTAL; j += 128) {
        const float n = sqrtf(G[(size_t)j * N_TOTAL + j]);
        sInv[j] = 1.0f / fmaxf(n, EPS);
    }
    __syncthreads();

    const float mi  = sInv[i] * 10.0f;   // 1/temp = 10
    const int   myc = i & 7;
    float s = 0.0f;
    for (int j = threadIdx.x; j < N_TOTAL; j += 128) {
        if ((j & 7) != myc)
            s += expf(gsym(G, i, j) * mi * sInv[j]);
    }
#pragma unroll
    for (int off = 32; off > 0; off >>= 1) s += __shfl_down(s, off, 64);
    __shared__ float partial[2];
    if ((threadIdx.x & 63) == 0) partial[threadIdx.x >> 6] = s;
    __syncthreads();
    if (threadIdx.x == 0) den[i] = partial[0] + partial[1];
}

__global__ __launch_bounds__(256) void loss_kernel(const float* __restrict__ G,
                                                   const float* __restrict__ den,
                                                   float* __restrict__ out) {
    __shared__ float sInv[N_TOTAL];
    for (int j = threadIdx.x; j < N_TOTAL; j += 256) {
        const float n = sqrtf(G[(size_t)j * N_TOTAL + j]);
        sInv[j] = 1.0f / fmaxf(n, EPS);
    }
    __syncthreads();

    float s = 0.0f;
    for (int idx = threadIdx.x; idx < 7 * BS; idx += 256) {
        const int p   = idx & (BS - 1);
        const int set = idx >> 7;
        int a, b;
        switch (set) {
            case 0:  a = p;                        b = BS + p;                      break;
            case 1:  a = (p + PD) % N_TOTAL;       b = (BS + p + PD) % N_TOTAL;     break;
            case 2:  a = p;                        b = (p + PD) % N_TOTAL;          break;
            case 3:  a = BS + p;                   b = (BS + p + PD) % N_TOTAL;     break;
            case 4:  a = 2 * BS + p;               b = (2 * BS + p + PD) % N_TOTAL; break;
            case 5:  a = BS + p;                   b = 2 * BS + p;                  break;
            default: a = (BS + p + PD) % N_TOTAL;  b = (2 * BS + p + PD) % N_TOTAL; break;
        }
        const float en = expf(gsym(G, a, b) * sInv[a] * sInv[b] * 10.0f);
        s += log1pf(den[a] / en) + log1pf(den[b] / en);
    }
#pragma unroll
    for (int off = 32; off > 0; off >>= 1) s += __shfl_down(s, off, 64);
    __shared__ float partial[4];
    if ((threadIdx.x & 63) == 0) partial[threadIdx.x >> 6] = s;
    __syncthreads();
    if (threadIdx.x == 0)
        out[0] = (partial[0] + partial[1] + partial[2] + partial[3]) / 768.0f;
}

extern "C" void kernel_launch(void* const* d_in, const int* in_sizes, int n_in,
                              void* d_out, int out_size, void* d_ws, size_t ws_size,
                              hipStream_t stream) {
    (void)in_sizes; (void)n_in; (void)out_size; (void)ws_size;
    const float* X   = (const float*)d_in[0];
    float*       out = (float*)d_out;
    float*       G   = (float*)d_ws;                          // 384*384 fp32
    float*       den = G + (size_t)N_TOTAL * N_TOTAL;         // 384 fp32
    __bf16*      P   = (__bf16*)((char*)d_ws + (1u << 20));   // 256*24*4096 bf16 = 48 MB

    gram_fused_kernel<<<NSTRIP, 512, 0, stream>>>(X, P);
    reduce_kernel<<<NSLOT * 16, 256, 0, stream>>>(P, G);
    den_kernel<<<N_TOTAL, 128, 0, stream>>>(G, den);
    loss_kernel<<<1, 256, 0, stream>>>(G, den, out);
}

// Round 10
// 72.746 us; speedup vs baseline: 1.2311x; 1.2311x over previous
//
#include <hip/hip_runtime.h>
#include <hip/hip_bf16.h>

#define N_TOTAL 384
#define BS 128
#define PD 8
#define D_FEAT 131072
#define EPS 1e-6f

#define NSTRIP 256
#define COLS_PER (D_FEAT / NSTRIP)    // 512 cols per strip
#define CHUNK 32
#define NCH (COLS_PER / CHUNK)        // 16 chunks per strip
#define NSLOT 24                      // subtile partials per block (all 24)

typedef __attribute__((ext_vector_type(4))) float f32x4;
typedef __attribute__((ext_vector_type(8))) __bf16 bf16x8;
typedef __attribute__((ext_vector_type(4))) __bf16 bf16x4;

typedef __attribute__((address_space(1))) const unsigned int gu32;
typedef __attribute__((address_space(3))) unsigned int lu32;

__device__ __forceinline__ void gload16(const void* g, void* l) {
    // async global->LDS DMA, 16 B/lane; LDS dest = wave-uniform base + lane*16
    __builtin_amdgcn_global_load_lds((gu32*)g, (lu32*)l, 16, 0, 0);
}

// Per-wave subtile tables: wave w owns 3 (A-band, B-band) pairs; first two share A.
// Covers the 24 stored band-pairs exactly once:
// a=0:B{0..5}, a=1:B{0..5}, a=2:B{2..5}, a=3:B{2..5}, a=4:B{4,5}, a=5:B{4,5}.
static __device__ const int SAt[8][3] = {{0,0,0},{0,0,0},{1,1,1},{1,1,1},
                                         {2,2,4},{2,2,4},{3,3,5},{3,3,5}};
static __device__ const int SBt[8][3] = {{0,1,2},{3,4,5},{0,1,2},{3,4,5},
                                         {2,3,4},{4,5,5},{2,3,4},{4,5,5}};
// slot = wave*3 + s -> (row-band, col-band) for the reducer (flattened copies)
static __device__ const int SRB2[NSLOT] = {0,0,0, 0,0,0, 1,1,1, 1,1,1,
                                           2,2,4, 2,2,4, 3,3,5, 3,3,5};
static __device__ const int SCB2[NSLOT] = {0,1,2, 3,4,5, 0,1,2, 3,4,5,
                                           2,3,4, 4,5,5, 2,3,4, 4,5,5};

// Symmetric accessor: only the 24 stored subtiles of G are populated.
__device__ __forceinline__ float gsym(const float* __restrict__ G, int i, int j) {
    return ((i >> 7) <= (j >> 7)) ? G[(size_t)i * N_TOTAL + j]
                                  : G[(size_t)j * N_TOTAL + i];
}

// LDS fragment load: row-major fp32 [384][32] with 16B-granule swizzle
// phys_granule = logical_granule ^ (row & 7). Convert 8 f32 -> bf16x8.
__device__ __forceinline__ bf16x8 fragld(const char* bptr, int row, int kg) {
    const int k = row & 7;
    const f32x4 lo = *(const f32x4*)(bptr + row * 128 + (((2 * kg)     ^ k) * 16));
    const f32x4 hi = *(const f32x4*)(bptr + row * 128 + (((2 * kg + 1) ^ k) * 16));
    bf16x8 r;
    r[0] = (__bf16)lo[0]; r[1] = (__bf16)lo[1]; r[2] = (__bf16)lo[2]; r[3] = (__bf16)lo[3];
    r[4] = (__bf16)hi[0]; r[5] = (__bf16)hi[1]; r[6] = (__bf16)hi[2]; r[7] = (__bf16)hi[3];
    return r;
}

// ---- stage A: one block per strip, X read ONCE (201 MB total), async fp32->LDS,
// ---- cvt per fragment, all 24 subtile partials, NO atomics, NO staging regs.
__global__ __launch_bounds__(512) void gram_fused_kernel(const float* __restrict__ X,
                                                         __bf16* __restrict__ P) {
    __shared__ char sm[2][N_TOTAL * 128];   // 2 x 48 KB: fp32 [384][32], granule-swizzled

    const int strip = blockIdx.x;
    const int tid  = threadIdx.x;
    const int wave = tid >> 6;
    const int lane = tid & 63;
    const int r16  = lane & 15;
    const int kg   = lane >> 4;

    const int A0 = SAt[wave][0] * 64, A2 = SAt[wave][2] * 64;
    const int B0 = SBt[wave][0] * 64, B1 = SBt[wave][1] * 64, B2 = SBt[wave][2] * 64;

    // Staging geometry: issue s covers rows s*64 + (tid>>3), phys granule tid&7.
    // Source carries the inverse (= same) XOR so LDS-linear DMA lands swizzled.
    const int lg = (tid & 7) ^ ((tid >> 3) & 7);   // logical granule for this lane
    const char* src0 = (const char*)(X + (size_t)(tid >> 3) * D_FEAT
                                       + (size_t)strip * COLS_PER) + lg * 16;

    f32x4 acc0[4][4], acc1[4][4], acc2[4][4];
#pragma unroll
    for (int m = 0; m < 4; m++)
#pragma unroll
        for (int n = 0; n < 4; n++) {
            acc0[m][n] = (f32x4)(0.0f); acc1[m][n] = (f32x4)(0.0f); acc2[m][n] = (f32x4)(0.0f);
        }

#define STAGE(buf, t)                                                                     \
    _Pragma("unroll") for (int s = 0; s < 6; s++)                                         \
        gload16(src0 + (size_t)s * (64ull * D_FEAT * 4) + (size_t)(t) * 128,              \
                (char*)sm[buf] + s * 8192 + tid * 16);

#define SUBT(accX, Bb)                                                                    \
    do {                                                                                  \
        bf16x8 bf[4];                                                                     \
        _Pragma("unroll") for (int n = 0; n < 4; n++)                                     \
            bf[n] = fragld(bptr, (Bb) + n * 16 + r16, kg);                                \
        _Pragma("unroll") for (int m = 0; m < 4; m++)                                     \
            _Pragma("unroll") for (int n = 0; n < 4; n++)                                 \
                accX[m][n] = __builtin_amdgcn_mfma_f32_16x16x32_bf16(af[m], bf[n],        \
                                                                     accX[m][n], 0, 0, 0);\
    } while (0)

    STAGE(0, 0);
    __syncthreads();    // drains vmcnt(0): buf0 ready

    for (int t = 0; t < NCH; ++t) {
        const int b = t & 1;
        if (t + 1 < NCH) STAGE(b ^ 1, t + 1);   // in flight during compute below
        const char* bptr = sm[b];
        bf16x8 af[4];
#pragma unroll
        for (int m = 0; m < 4; m++) af[m] = fragld(bptr, A0 + m * 16 + r16, kg);
        SUBT(acc0, B0);
        SUBT(acc1, B1);
#pragma unroll
        for (int m = 0; m < 4; m++) af[m] = fragld(bptr, A2 + m * 16 + r16, kg);  // reuse
        SUBT(acc2, B2);
        __syncthreads();   // drains next-buffer stage + protects buffer reuse
    }
#undef STAGE
#undef SUBT

    // Epilogue: per-wave 64x64 partials as bf16, col-major (bf16x4 over rows).
    // C/D layout: ccol = lane&15 (B-side), crow = (lane>>4)*4 + r (A-side).
    const int crow = (lane >> 4) * 4;
    const int ccol = lane & 15;
#define STOREP(accX, s)                                                                   \
    do {                                                                                  \
        __bf16* base = P + ((size_t)strip * NSLOT + wave * 3 + (s)) * 4096;               \
        _Pragma("unroll") for (int m = 0; m < 4; m++)                                     \
            _Pragma("unroll") for (int n = 0; n < 4; n++) {                               \
                bf16x4 v;                                                                 \
                v[0] = (__bf16)accX[m][n][0]; v[1] = (__bf16)accX[m][n][1];               \
                v[2] = (__bf16)accX[m][n][2]; v[3] = (__bf16)accX[m][n][3];               \
                *(bf16x4*)(base + (n * 16 + ccol) * 64 + m * 16 + crow) = v;              \
            }                                                                             \
    } while (0)
    STOREP(acc0, 0);
    STOREP(acc1, 1);
    STOREP(acc2, 2);
#undef STOREP
}

// ---- stage B: reduce bf16 partials over 256 strips -> G (fp32) ----
__global__ __launch_bounds__(256) void reduce_kernel(const __bf16* __restrict__ P,
                                                     float* __restrict__ G) {
    const int b     = blockIdx.x;                  // 0..383
    const int chunk = b & 15;                      // 16 chunks of 256 elems
    const int slot  = b >> 4;                      // 0..23
    const int e     = chunk * 256 + threadIdx.x;   // 0..4095

    const __bf16* p = P + (size_t)slot * 4096 + e;
    float s = 0.0f;
#pragma unroll 16
    for (int strip = 0; strip < NSTRIP; ++strip)
        s += (float)p[(size_t)strip * NSLOT * 4096];

    const int rb  = SRB2[slot] * 64;
    const int cb  = SCB2[slot] * 64;
    const int col = e >> 6;
    const int row = e & 63;
    G[(size_t)(rb + row) * N_TOTAL + cb + col] = s;
}

// ---------------- denominators and loss ----------------
__global__ __launch_bounds__(128) void den_kernel(const float* __restrict__ G,
                                                  float* __restrict__ den) {
    const int i = blockIdx.x;
    __shared__ float sInv[N_TOTAL];
    for (int j = threadIdx.x; j < N_TOTAL; j += 128) {
        const float n = sqrtf(G[(size_t)j * N_TOTAL + j]);
        sInv[j] = 1.0f / fmaxf(n, EPS);
    }
    __syncthreads();

    const float mi  = sInv[i] * 10.0f;   // 1/temp = 10
    const int   myc = i & 7;
    float s = 0.0f;
    for (int j = threadIdx.x; j < N_TOTAL; j += 128) {
        if ((j & 7) != myc)
            s += expf(gsym(G, i, j) * mi * sInv[j]);
    }
#pragma unroll
    for (int off = 32; off > 0; off >>= 1) s += __shfl_down(s, off, 64);
    __shared__ float partial[2];
    if ((threadIdx.x & 63) == 0) partial[threadIdx.x >> 6] = s;
    __syncthreads();
    if (threadIdx.x == 0) den[i] = partial[0] + partial[1];
}

__global__ __launch_bounds__(256) void loss_kernel(const float* __restrict__ G,
                                                   const float* __restrict__ den,
                                                   float* __restrict__ out) {
    __shared__ float sInv[N_TOTAL];
    for (int j = threadIdx.x; j < N_TOTAL; j += 256) {
        const float n = sqrtf(G[(size_t)j * N_TOTAL + j]);
        sInv[j] = 1.0f / fmaxf(n, EPS);
    }
    __syncthreads();

    float s = 0.0f;
    for (int idx = threadIdx.x; idx < 7 * BS; idx += 256) {
        const int p   = idx & (BS - 1);
        const int set = idx >> 7;
        int a, b;
        switch (set) {
            case 0:  a = p;                        b = BS + p;                      break;
            case 1:  a = (p + PD) % N_TOTAL;       b = (BS + p + PD) % N_TOTAL;     break;
            case 2:  a = p;                        b = (p + PD) % N_TOTAL;          break;
            case 3:  a = BS + p;                   b = (BS + p + PD) % N_TOTAL;     break;
            case 4:  a = 2 * BS + p;               b = (2 * BS + p + PD) % N_TOTAL; break;
            case 5:  a = BS + p;                   b = 2 * BS + p;                  break;
            default: a = (BS + p + PD) % N_TOTAL;  b = (2 * BS + p + PD) % N_TOTAL; break;
        }
        const float en = expf(gsym(G, a, b) * sInv[a] * sInv[b] * 10.0f);
        s += log1pf(den[a] / en) + log1pf(den[b] / en);
    }
#pragma unroll
    for (int off = 32; off > 0; off >>= 1) s += __shfl_down(s, off, 64);
    __shared__ float partial[4];
    if ((threadIdx.x & 63) == 0) partial[threadIdx.x >> 6] = s;
    __syncthreads();
    if (threadIdx.x == 0)
        out[0] = (partial[0] + partial[1] + partial[2] + partial[3]) / 768.0f;
}

extern "C" void kernel_launch(void* const* d_in, const int* in_sizes, int n_in,
                              void* d_out, int out_size, void* d_ws, size_t ws_size,
                              hipStream_t stream) {
    (void)in_sizes; (void)n_in; (void)out_size; (void)ws_size;
    const float* X   = (const float*)d_in[0];
    float*       out = (float*)d_out;
    float*       G   = (float*)d_ws;                          // 384*384 fp32 (only the
    float*       den = G + (size_t)N_TOTAL * N_TOTAL;         //  24 stored subtiles used)
    __bf16*      P   = (__bf16*)((char*)d_ws + (1u << 20));   // 256*24*4096 bf16 = 50 MB

    gram_fused_kernel<<<NSTRIP, 512, 0, stream>>>(X, P);
    reduce_kernel<<<NSLOT * 16, 256, 0, stream>>>(P, G);
    den_kernel<<<N_TOTAL, 128, 0, stream>>>(G, den);
    loss_kernel<<<1, 256, 0, stream>>>(G, den, out);
}